// Round 4
// baseline (558.644 us; speedup 1.0000x reference)
//
#include <hip/hip_runtime.h>
#include <hip/hip_bf16.h>
#include <cstdint>
#include <cstddef>

// Problem constants
#define T_DIM   2048
#define HID     4096
#define HQ      32
#define HKV     8
#define D_HEAD  128
#define QKV_N   6144   // 4096 Q + 1024 K + 1024 V
#define KOFF    4096
#define VOFF    5120

typedef __attribute__((ext_vector_type(8))) short short8;   // 8 bf16 (4 VGPRs)
typedef __attribute__((ext_vector_type(4))) float floatx4;  // MFMA C/D frag

__device__ __forceinline__ ushort f2bf(float f) {
    union { float f; uint u; } v; v.f = f;
    uint r = v.u + 0x7fffu + ((v.u >> 16) & 1u);  // RNE
    return (ushort)(r >> 16);
}
__device__ __forceinline__ float bf2f(ushort h) {
    union { uint u; float f; } v; v.u = ((uint)h) << 16; return v.f;
}
// 8 bf16 from 8B-aligned LDS
__device__ __forceinline__ short8 ld8(const ushort* p) {
    uint2 a = *(const uint2*)p, b = *(const uint2*)(p + 4);
    union { uint u[4]; short8 s; } x;
    x.u[0] = a.x; x.u[1] = a.y; x.u[2] = b.x; x.u[3] = b.y;
    return x.s;
}
// async global->LDS, 16B per lane. LDS dest must be wave-uniform base + lane*16.
__device__ __forceinline__ void gld_lds16(const ushort* g, ushort* l) {
    __builtin_amdgcn_global_load_lds(
        (__attribute__((address_space(1))) void*)(g),
        (__attribute__((address_space(3))) void*)(l), 16, 0, 0);
}

// ---------------- elementwise cast fp32 -> bf16 ----------------
__global__ void cast_f32_bf16(const float* __restrict__ in, ushort* __restrict__ out, int n) {
    int i = (blockIdx.x * blockDim.x + threadIdx.x) * 4;
    if (i < n) {
        float4 v = *(const float4*)(in + i);
        ushort4 o;
        o.x = f2bf(v.x); o.y = f2bf(v.y); o.z = f2bf(v.z); o.w = f2bf(v.w);
        *(ushort4*)(out + i) = o;
    }
}

// ---------------- transpose + cast: W[K][N] fp32 -> Wt[N][K] bf16 ----------------
__global__ __launch_bounds__(256) void transpose_cast(const float* __restrict__ W,
                                                      ushort* __restrict__ Wt, int K, int N) {
    __shared__ ushort tile[64][72];
    int n0 = blockIdx.x * 64, k0 = blockIdx.y * 64;
    int tx = threadIdx.x & 15, ty = threadIdx.x >> 4;  // 16 x 16
#pragma unroll
    for (int i = 0; i < 4; i++) {
        int r = ty + i * 16;  // k-row
        float4 v = *(const float4*)&W[(size_t)(k0 + r) * N + n0 + tx * 4];
        tile[tx * 4 + 0][r] = f2bf(v.x);
        tile[tx * 4 + 1][r] = f2bf(v.y);
        tile[tx * 4 + 2][r] = f2bf(v.z);
        tile[tx * 4 + 3][r] = f2bf(v.w);
    }
    __syncthreads();
#pragma unroll
    for (int i = 0; i < 2; i++) {
        int task = i * 256 + threadIdx.x;
        int nr = task >> 3, c = task & 7;
        short8 o = *(const short8*)&tile[nr][c * 8];
        *(short8*)&Wt[(size_t)(n0 + nr) * K + k0 + c * 8] = o;
    }
}

// ---------------- transpose V slice of qkv -> VtG[kvh][d][t] (t contiguous) ----------------
__global__ void transpose_v(const ushort* __restrict__ qkv, ushort* __restrict__ VtG) {
    __shared__ ushort tile[32][33];
    int t0 = blockIdx.x * 32, d0 = blockIdx.y * 32, kvh = blockIdx.z;
    int tx = threadIdx.x & 31, ty = threadIdx.x >> 5;  // 32 x 8
#pragma unroll
    for (int i = 0; i < 4; i++) {
        int t = t0 + ty + i * 8;
        tile[ty + i * 8][tx] = qkv[(size_t)t * QKV_N + VOFF + kvh * D_HEAD + d0 + tx];
    }
    __syncthreads();
#pragma unroll
    for (int i = 0; i < 4; i++) {
        int d = d0 + ty + i * 8;
        VtG[((size_t)kvh * D_HEAD + d) * T_DIM + t0 + tx] = tile[tx][ty + i * 8];
    }
}

// ======== QKV GEMM: BM=256 x BN=192, BK=64, 8 waves (2Mx4N), grid 8x32 = 256 = 1/CU ========
// 4 phases per K-tile (one 32-row M-quadrant x K=64 x 3 N-frags = 12 MFMA each).
// LDS: As 2x32KB (4 row-issues of 64) + Bs 2x24KB (3 issues) = 112 KiB -> 1 block/CU.
// Staging of tile t+1 during tile t: P0:[B0,B1] P1:[B2,A0] P2:[A2] P3:[A1,A3].
// Read needs: P0 needs B0..B2 + A0(wr0)/A2(wr1); P2/P3 need A1/A3.
// FIFO-derived counted waits (steady): end-P1 vmcnt(4) [drains A1,A3 of t];
// end-P3 vmcnt(2) [drains B0',B1',B2',A0',A2']. Tail: vmcnt(0) at end-P1, none at P3.
// Swizzle: global source chunk csw = (tid&7) ^ (row&7); reads XOR with l15&7 -> conflict-free.
__global__ __launch_bounds__(512, 1) void gemm_qkv(const ushort* __restrict__ A,
                                                   const ushort* __restrict__ Bt,
                                                   ushort* __restrict__ C,
                                                   int K, int lda, int ldb, int ldc) {
    __shared__ ushort As[2][16384];
    __shared__ ushort Bs[2][12288];
    int tid = threadIdx.x;
    int wid = tid >> 6, lane = tid & 63, quad = lane >> 4, l15 = lane & 15;
    int wr = wid >> 2, wc = wid & 3;
    int m0 = blockIdx.x * 256, n0 = blockIdx.y * 192;
    int sw = l15 & 7;

    floatx4 acc[8][3];
    floatx4 z = {0.f, 0.f, 0.f, 0.f};
#pragma unroll
    for (int i = 0; i < 8; i++)
#pragma unroll
        for (int j = 0; j < 3; j++) acc[i][j] = z;

    int NT = K >> 6;
    int r8 = tid >> 3;
    int csw = (tid & 7) ^ (r8 & 7);
    const ushort* sA = A + (size_t)(m0 + r8) * lda + csw * 8;
    const ushort* sB = Bt + (size_t)(n0 + r8) * ldb + csw * 8;

    // prologue: tile0 items in order [B0,B1,B2,A0,A2,A1,A3]
    gld_lds16(sB,                      &Bs[0][tid * 8]);
    gld_lds16(sB + (size_t)64 * ldb,   &Bs[0][4096 + tid * 8]);
    gld_lds16(sB + (size_t)128 * ldb,  &Bs[0][8192 + tid * 8]);
    gld_lds16(sA,                      &As[0][tid * 8]);
    gld_lds16(sA + (size_t)128 * lda,  &As[0][8192 + tid * 8]);
    gld_lds16(sA + (size_t)64 * lda,   &As[0][4096 + tid * 8]);
    gld_lds16(sA + (size_t)192 * lda,  &As[0][12288 + tid * 8]);
    asm volatile("s_waitcnt vmcnt(2)" ::: "memory");
    __builtin_amdgcn_sched_barrier(0);
    __builtin_amdgcn_s_barrier();

    short8 bfr[3][2];
    short8 af[2][2];

    for (int t = 0; t < NT; ++t) {
        int slot = t & 1, ns = slot ^ 1;
        const ushort* tA = &As[slot][0];
        const ushort* tB = &Bs[slot][0];
        size_t ko = (size_t)(t + 1) * 64;
        bool pf = (t + 1 < NT);

        // ---------------- P0: all B frags + A quadrant 0; issue B0',B1' ----------------
#pragma unroll
        for (int nf = 0; nf < 3; ++nf)
#pragma unroll
            for (int kh = 0; kh < 2; ++kh)
                bfr[nf][kh] = *(const short8*)&tB[(wc * 48 + nf * 16 + l15) * 64 +
                                                  (((quad + kh * 4) ^ sw) * 8)];
#pragma unroll
        for (int mi = 0; mi < 2; ++mi)
#pragma unroll
            for (int kh = 0; kh < 2; ++kh)
                af[mi][kh] = *(const short8*)&tA[(wr * 128 + mi * 16 + l15) * 64 +
                                                 (((quad + kh * 4) ^ sw) * 8)];
        if (pf) {
            gld_lds16(sB + ko,                    &Bs[ns][tid * 8]);
            gld_lds16(sB + (size_t)64 * ldb + ko, &Bs[ns][4096 + tid * 8]);
        }
        __builtin_amdgcn_sched_barrier(0);
        __builtin_amdgcn_s_barrier();
        asm volatile("s_waitcnt lgkmcnt(0)" ::: "memory");
        __builtin_amdgcn_sched_barrier(0);
        __builtin_amdgcn_s_setprio(1);
#pragma unroll
        for (int nf = 0; nf < 3; ++nf)
#pragma unroll
            for (int mi = 0; mi < 2; ++mi)
#pragma unroll
                for (int kh = 0; kh < 2; ++kh)
                    acc[mi][nf] = __builtin_amdgcn_mfma_f32_16x16x32_bf16(af[mi][kh], bfr[nf][kh], acc[mi][nf], 0, 0, 0);
        __builtin_amdgcn_s_setprio(0);
        __builtin_amdgcn_sched_barrier(0);
        __builtin_amdgcn_s_barrier();

        // ---------------- P1: A quadrant 1; issue B2',A0'; end: vmcnt(4|0) ----------------
#pragma unroll
        for (int mi = 0; mi < 2; ++mi)
#pragma unroll
            for (int kh = 0; kh < 2; ++kh)
                af[mi][kh] = *(const short8*)&tA[(wr * 128 + 32 + mi * 16 + l15) * 64 +
                                                 (((quad + kh * 4) ^ sw) * 8)];
        if (pf) {
            gld_lds16(sB + (size_t)128 * ldb + ko, &Bs[ns][8192 + tid * 8]);
            gld_lds16(sA + ko,                     &As[ns][tid * 8]);
        }
        __builtin_amdgcn_sched_barrier(0);
        __builtin_amdgcn_s_barrier();
        asm volatile("s_waitcnt lgkmcnt(0)" ::: "memory");
        __builtin_amdgcn_sched_barrier(0);
        __builtin_amdgcn_s_setprio(1);
#pragma unroll
        for (int nf = 0; nf < 3; ++nf)
#pragma unroll
            for (int mi = 0; mi < 2; ++mi)
#pragma unroll
                for (int kh = 0; kh < 2; ++kh)
                    acc[2 + mi][nf] = __builtin_amdgcn_mfma_f32_16x16x32_bf16(af[mi][kh], bfr[nf][kh], acc[2 + mi][nf], 0, 0, 0);
        __builtin_amdgcn_s_setprio(0);
        __builtin_amdgcn_sched_barrier(0);
        if (pf) asm volatile("s_waitcnt vmcnt(4)" ::: "memory");
        else    asm volatile("s_waitcnt vmcnt(0)" ::: "memory");
        __builtin_amdgcn_sched_barrier(0);
        __builtin_amdgcn_s_barrier();

        // ---------------- P2: A quadrant 2; issue A2' ----------------
#pragma unroll
        for (int mi = 0; mi < 2; ++mi)
#pragma unroll
            for (int kh = 0; kh < 2; ++kh)
                af[mi][kh] = *(const short8*)&tA[(wr * 128 + 64 + mi * 16 + l15) * 64 +
                                                 (((quad + kh * 4) ^ sw) * 8)];
        if (pf) {
            gld_lds16(sA + (size_t)128 * lda + ko, &As[ns][8192 + tid * 8]);
        }
        __builtin_amdgcn_sched_barrier(0);
        __builtin_amdgcn_s_barrier();
        asm volatile("s_waitcnt lgkmcnt(0)" ::: "memory");
        __builtin_amdgcn_sched_barrier(0);
        __builtin_amdgcn_s_setprio(1);
#pragma unroll
        for (int nf = 0; nf < 3; ++nf)
#pragma unroll
            for (int mi = 0; mi < 2; ++mi)
#pragma unroll
                for (int kh = 0; kh < 2; ++kh)
                    acc[4 + mi][nf] = __builtin_amdgcn_mfma_f32_16x16x32_bf16(af[mi][kh], bfr[nf][kh], acc[4 + mi][nf], 0, 0, 0);
        __builtin_amdgcn_s_setprio(0);
        __builtin_amdgcn_sched_barrier(0);
        __builtin_amdgcn_s_barrier();

        // ---------------- P3: A quadrant 3; issue A1',A3'; end: vmcnt(2) ----------------
#pragma unroll
        for (int mi = 0; mi < 2; ++mi)
#pragma unroll
            for (int kh = 0; kh < 2; ++kh)
                af[mi][kh] = *(const short8*)&tA[(wr * 128 + 96 + mi * 16 + l15) * 64 +
                                                 (((quad + kh * 4) ^ sw) * 8)];
        if (pf) {
            gld_lds16(sA + (size_t)64 * lda + ko,  &As[ns][4096 + tid * 8]);
            gld_lds16(sA + (size_t)192 * lda + ko, &As[ns][12288 + tid * 8]);
        }
        __builtin_amdgcn_sched_barrier(0);
        __builtin_amdgcn_s_barrier();
        asm volatile("s_waitcnt lgkmcnt(0)" ::: "memory");
        __builtin_amdgcn_sched_barrier(0);
        __builtin_amdgcn_s_setprio(1);
#pragma unroll
        for (int nf = 0; nf < 3; ++nf)
#pragma unroll
            for (int mi = 0; mi < 2; ++mi)
#pragma unroll
                for (int kh = 0; kh < 2; ++kh)
                    acc[6 + mi][nf] = __builtin_amdgcn_mfma_f32_16x16x32_bf16(af[mi][kh], bfr[nf][kh], acc[6 + mi][nf], 0, 0, 0);
        __builtin_amdgcn_s_setprio(0);
        __builtin_amdgcn_sched_barrier(0);
        if (pf) asm volatile("s_waitcnt vmcnt(2)" ::: "memory");
        __builtin_amdgcn_sched_barrier(0);
        __builtin_amdgcn_s_barrier();
    }

    // epilogue: acc[i] -> rows m0 + wr*128 + i*16 + quad*4 + r ; col n0 + wc*48 + j*16 + l15
#pragma unroll
    for (int i = 0; i < 8; ++i) {
        int row0 = m0 + wr * 128 + i * 16 + quad * 4;
#pragma unroll
        for (int j = 0; j < 3; ++j) {
            int col = n0 + wc * 48 + j * 16 + l15;
#pragma unroll
            for (int r = 0; r < 4; ++r)
                C[(size_t)(row0 + r) * ldc + col] = f2bf(acc[i][j][r]);
        }
    }
}

// ======== O-proj GEMM: BM=256 x BN=128, BK=64, 8 waves (2Mx4N), grid 8x32 = 256 = 1/CU ========
// 2 phases per K-tile (one 64-row M-half x K=64 x 2 N-frags = 16 MFMA each).
// LDS: As 2x32KB + Bs 2x16KB = 96 KiB. Staging of t+1: P0:[B0,B1,A0] P1:[A2,A1,A3].
// Reads: P0 needs B0,B1 + A0(wr0)/A2(wr1); P1 needs A1/A3.
// Counted waits (FIFO-derived): end-P0 vmcnt(3) [drains A1,A3 of t];
// end-P1 vmcnt(2) [drains B0',B1',A0',A2']. Tail: vmcnt(0) at end-P0, none at P1.
__global__ __launch_bounds__(512, 1) void gemm_out(const ushort* __restrict__ A,
                                                   const ushort* __restrict__ Bt,
                                                   float* __restrict__ C,
                                                   int K, int lda, int ldb, int ldc) {
    __shared__ ushort As[2][16384];
    __shared__ ushort Bs[2][8192];
    int tid = threadIdx.x;
    int wid = tid >> 6, lane = tid & 63, quad = lane >> 4, l15 = lane & 15;
    int wr = wid >> 2, wc = wid & 3;
    int m0 = blockIdx.x * 256, n0 = blockIdx.y * 128;
    int sw = l15 & 7;

    floatx4 acc[8][2];
    floatx4 z = {0.f, 0.f, 0.f, 0.f};
#pragma unroll
    for (int i = 0; i < 8; i++)
#pragma unroll
        for (int j = 0; j < 2; j++) acc[i][j] = z;

    int NT = K >> 6;
    int r8 = tid >> 3;
    int csw = (tid & 7) ^ (r8 & 7);
    const ushort* sA = A + (size_t)(m0 + r8) * lda + csw * 8;
    const ushort* sB = Bt + (size_t)(n0 + r8) * ldb + csw * 8;

    // prologue: tile0 items in order [B0,B1,A0,A2,A1,A3]
    gld_lds16(sB,                      &Bs[0][tid * 8]);
    gld_lds16(sB + (size_t)64 * ldb,   &Bs[0][4096 + tid * 8]);
    gld_lds16(sA,                      &As[0][tid * 8]);
    gld_lds16(sA + (size_t)128 * lda,  &As[0][8192 + tid * 8]);
    gld_lds16(sA + (size_t)64 * lda,   &As[0][4096 + tid * 8]);
    gld_lds16(sA + (size_t)192 * lda,  &As[0][12288 + tid * 8]);
    asm volatile("s_waitcnt vmcnt(2)" ::: "memory");
    __builtin_amdgcn_sched_barrier(0);
    __builtin_amdgcn_s_barrier();

    short8 bfr[2][2];
    short8 af[4][2];

    for (int t = 0; t < NT; ++t) {
        int slot = t & 1, ns = slot ^ 1;
        const ushort* tA = &As[slot][0];
        const ushort* tB = &Bs[slot][0];
        size_t ko = (size_t)(t + 1) * 64;
        bool pf = (t + 1 < NT);

        // ---------------- P0: B frags + A half 0; issue B0',B1',A0'; end: vmcnt(3|0) ----------------
#pragma unroll
        for (int nf = 0; nf < 2; ++nf)
#pragma unroll
            for (int kh = 0; kh < 2; ++kh)
                bfr[nf][kh] = *(const short8*)&tB[(wc * 32 + nf * 16 + l15) * 64 +
                                                  (((quad + kh * 4) ^ sw) * 8)];
#pragma unroll
        for (int mi = 0; mi < 4; ++mi)
#pragma unroll
            for (int kh = 0; kh < 2; ++kh)
                af[mi][kh] = *(const short8*)&tA[(wr * 128 + mi * 16 + l15) * 64 +
                                                 (((quad + kh * 4) ^ sw) * 8)];
        if (pf) {
            gld_lds16(sB + ko,                    &Bs[ns][tid * 8]);
            gld_lds16(sB + (size_t)64 * ldb + ko, &Bs[ns][4096 + tid * 8]);
            gld_lds16(sA + ko,                    &As[ns][tid * 8]);
        }
        __builtin_amdgcn_sched_barrier(0);
        __builtin_amdgcn_s_barrier();
        asm volatile("s_waitcnt lgkmcnt(0)" ::: "memory");
        __builtin_amdgcn_sched_barrier(0);
        __builtin_amdgcn_s_setprio(1);
#pragma unroll
        for (int nf = 0; nf < 2; ++nf)
#pragma unroll
            for (int mi = 0; mi < 4; ++mi)
#pragma unroll
                for (int kh = 0; kh < 2; ++kh)
                    acc[mi][nf] = __builtin_amdgcn_mfma_f32_16x16x32_bf16(af[mi][kh], bfr[nf][kh], acc[mi][nf], 0, 0, 0);
        __builtin_amdgcn_s_setprio(0);
        __builtin_amdgcn_sched_barrier(0);
        if (pf) asm volatile("s_waitcnt vmcnt(3)" ::: "memory");
        else    asm volatile("s_waitcnt vmcnt(0)" ::: "memory");
        __builtin_amdgcn_sched_barrier(0);
        __builtin_amdgcn_s_barrier();

        // ---------------- P1: A half 1; issue A2',A1',A3'; end: vmcnt(2) ----------------
#pragma unroll
        for (int mi = 0; mi < 4; ++mi)
#pragma unroll
            for (int kh = 0; kh < 2; ++kh)
                af[mi][kh] = *(const short8*)&tA[(wr * 128 + 64 + mi * 16 + l15) * 64 +
                                                 (((quad + kh * 4) ^ sw) * 8)];
        if (pf) {
            gld_lds16(sA + (size_t)128 * lda + ko, &As[ns][8192 + tid * 8]);
            gld_lds16(sA + (size_t)64 * lda + ko,  &As[ns][4096 + tid * 8]);
            gld_lds16(sA + (size_t)192 * lda + ko, &As[ns][12288 + tid * 8]);
        }
        __builtin_amdgcn_sched_barrier(0);
        __builtin_amdgcn_s_barrier();
        asm volatile("s_waitcnt lgkmcnt(0)" ::: "memory");
        __builtin_amdgcn_sched_barrier(0);
        __builtin_amdgcn_s_setprio(1);
#pragma unroll
        for (int nf = 0; nf < 2; ++nf)
#pragma unroll
            for (int mi = 0; mi < 4; ++mi)
#pragma unroll
                for (int kh = 0; kh < 2; ++kh)
                    acc[4 + mi][nf] = __builtin_amdgcn_mfma_f32_16x16x32_bf16(af[mi][kh], bfr[nf][kh], acc[4 + mi][nf], 0, 0, 0);
        __builtin_amdgcn_s_setprio(0);
        __builtin_amdgcn_sched_barrier(0);
        if (pf) asm volatile("s_waitcnt vmcnt(2)" ::: "memory");
        __builtin_amdgcn_sched_barrier(0);
        __builtin_amdgcn_s_barrier();
    }

    // epilogue
#pragma unroll
    for (int i = 0; i < 8; ++i) {
        int row0 = m0 + wr * 128 + i * 16 + quad * 4;
#pragma unroll
        for (int j = 0; j < 2; ++j) {
            int col = n0 + wc * 32 + j * 16 + l15;
#pragma unroll
            for (int r = 0; r < 4; ++r)
                C[(size_t)(row0 + r) * ldc + col] = acc[i][j][r];
        }
    }
}

// ---------------- RoPE in-place on Q and K slices of qkv ----------------
__global__ __launch_bounds__(320) void rope_kernel(ushort* __restrict__ qkv,
                                                   const float* __restrict__ cosb,
                                                   const float* __restrict__ sinb) {
    int t = blockIdx.x;
    ushort* row = qkv + (size_t)t * QKV_N;
    const float* cr = cosb + (size_t)t * D_HEAD;
    const float* sr = sinb + (size_t)t * D_HEAD;
    int task = threadIdx.x;            // 0..319
    int slice = task >> 3, d8 = (task & 7) * 8;
    int col = slice * 128 + d8;
    short8 a = *(const short8*)&row[col];
    short8 b = *(const short8*)&row[col + 64];
    float4 c0 = *(const float4*)&cr[d8], c1 = *(const float4*)&cr[d8 + 4];
    float4 s0 = *(const float4*)&sr[d8], s1 = *(const float4*)&sr[d8 + 4];
    short8 oa, ob;
#pragma unroll
    for (int j = 0; j < 8; j++) {
        float cs = (j < 4) ? ((j == 0) ? c0.x : (j == 1) ? c0.y : (j == 2) ? c0.z : c0.w)
                           : ((j == 4) ? c1.x : (j == 5) ? c1.y : (j == 6) ? c1.z : c1.w);
        float sn = (j < 4) ? ((j == 0) ? s0.x : (j == 1) ? s0.y : (j == 2) ? s0.z : s0.w)
                           : ((j == 4) ? s1.x : (j == 5) ? s1.y : (j == 6) ? s1.z : s1.w);
        float x0 = bf2f((ushort)a[j]), x1 = bf2f((ushort)b[j]);
        oa[j] = (short)f2bf(x0 * cs - x1 * sn);
        ob[j] = (short)f2bf(x1 * cs + x0 * sn);
    }
    *(short8*)&row[col] = oa;
    *(short8*)&row[col + 64] = ob;
}

// ---------------- flash-style causal GQA attention ----------------
#define PS_STRIDE 68

__global__ __launch_bounds__(256, 2) void attn_kernel(const ushort* __restrict__ qkv,
                                                      const ushort* __restrict__ VtG,
                                                      ushort* __restrict__ attn) {
    __shared__ ushort Ks[64 * 128];         // 16384 B, swizzled
    __shared__ ushort Vt[128 * 64];         // 16384 B, swizzled
    __shared__ ushort Ps[128 * PS_STRIDE];  // 17408 B  (total 50176 B -> 3 blocks/CU)

    int qt = (gridDim.x - 1) - blockIdx.x;  // heavy tiles dispatch first
    int h = blockIdx.y;
    int q0 = qt * 128;
    int kbmax = 2 * qt + 1;
    int tid = threadIdx.x, w = tid >> 6, lane = tid & 63, quad = lane >> 4, l15 = lane & 15;
    int kvh = h >> 2;                       // GQA group of 4

    const ushort* kbase = qkv + (size_t)KOFF + (size_t)kvh * D_HEAD;
    const ushort* vbase = VtG + (size_t)kvh * D_HEAD * T_DIM;

    const ushort* ksrc[4];
    const ushort* vsrc[4];
#pragma unroll
    for (int i = 0; i < 4; i++) {
        int cid = i * 256 + tid;
        int kr = cid >> 4, kp = cid & 15, kc = kp ^ (kr & 15);
        ksrc[i] = kbase + (size_t)kr * QKV_N + kc * 8;
        int vr = cid >> 3, vp = cid & 7, vc = vp ^ (vr & 7);
        vsrc[i] = vbase + (size_t)vr * T_DIM + vc * 8;
    }

    // prologue: issue K(0) loads (latency covered by the Q-frag loads below)
#pragma unroll
    for (int i = 0; i < 4; i++) {
        gld_lds16(ksrc[i], &Ks[(i * 256 + tid) * 8]);
        ksrc[i] += (size_t)64 * QKV_N;
    }

    // Q A-frags for both strips, direct from global (one-time scattered read)
    short8 qf[2][4];
#pragma unroll
    for (int s = 0; s < 2; s++) {
        const ushort* qrow = qkv + (size_t)(q0 + s * 64 + w * 16 + l15) * QKV_N + h * D_HEAD + quad * 8;
#pragma unroll
        for (int ks = 0; ks < 4; ks++)
            qf[s][ks] = *(const short8*)(qrow + ks * 32);
    }

    floatx4 o[2][8];
    floatx4 z = {0.f, 0.f, 0.f, 0.f};
#pragma unroll
    for (int s = 0; s < 2; s++)
#pragma unroll
        for (int j = 0; j < 8; j++) o[s][j] = z;
    float lsum[2][4] = {{0.f, 0.f, 0.f, 0.f}, {0.f, 0.f, 0.f, 0.f}};

    const float scale_l2e = 0.08838834764831845f * 1.4426950408889634f;  // D^-0.5 * log2(e)
    const float BOUND = 24.0f;

    __syncthreads();  // drain K(0)

    for (int kb = 0; kb <= kbmax; kb++) {
        bool act0 = (kb <= 2 * qt);  // strip0 fully masked on the final iteration

        // issue V(kb) loads (drained at mid-barrier; covered by QK compute)
#pragma unroll
        for (int i = 0; i < 4; i++) {
            gld_lds16(vsrc[i], &Vt[(i * 256 + tid) * 8]);
            vsrc[i] += 64;
        }

        // S = Q K^T for both strips; swizzled K frag reads shared across strips
        floatx4 sc[2][4];
#pragma unroll
        for (int s = 0; s < 2; s++)
#pragma unroll
            for (int jt = 0; jt < 4; jt++) sc[s][jt] = z;
#pragma unroll
        for (int ks = 0; ks < 4; ks++) {
#pragma unroll
            for (int jt = 0; jt < 4; jt++) {
                short8 kf = ld8(&Ks[(jt * 16 + l15) * 128 + (((ks * 4 + quad) ^ l15) * 8)]);
                if (act0)
                    sc[0][jt] = __builtin_amdgcn_mfma_f32_16x16x32_bf16(qf[0][ks], kf, sc[0][jt], 0, 0, 0);
                sc[1][jt] = __builtin_amdgcn_mfma_f32_16x16x32_bf16(qf[1][ks], kf, sc[1][jt], 0, 0, 0);
            }
        }

        // fixed-bound softmax; Ps rows are wave-private (lgkmcnt handles RAW)
#pragma unroll
        for (int s = 0; s < 2; s++) {
            if (s == 0 && !act0) continue;
            bool diag = (kb == 2 * qt + s);
#pragma unroll
            for (int r = 0; r < 4; r++) {
                int rloc = w * 16 + quad * 4 + r;  // row within strip
#pragma unroll
                for (int jt = 0; jt < 4; jt++) {
                    float v = fmaf(sc[s][jt][r], scale_l2e, -BOUND);
                    if (diag && (jt * 16 + l15 > rloc)) v = -1e30f;
                    float p = exp2f(v);
                    lsum[s][r] += p;
                    Ps[(s * 64 + rloc) * PS_STRIDE + jt * 16 + l15] = f2bf(p);
                }
            }
        }

        __syncthreads();  // drain V(kb); all waves' Ks reads complete

        // issue K(kb+1) loads (drained at end-barrier; covered by PV compute)
        if (kb < kbmax) {
#pragma unroll
            for (int i = 0; i < 4; i++) {
                gld_lds16(ksrc[i], &Ks[(i * 256 + tid) * 8]);
                ksrc[i] += (size_t)64 * QKV_N;
            }
        }

        // O += P V ; swizzled V frag reads shared across strips
#pragma unroll
        for (int ks2 = 0; ks2 < 2; ks2++) {
            short8 pf0 = ld8(&Ps[(w * 16 + l15) * PS_STRIDE + ks2 * 32 + quad * 8]);
            short8 pf1 = ld8(&Ps[(64 + w * 16 + l15) * PS_STRIDE + ks2 * 32 + quad * 8]);
#pragma unroll
            for (int jt = 0; jt < 8; jt++) {
                short8 vf = ld8(&Vt[(jt * 16 + l15) * 64 + (((ks2 * 4 + quad) ^ (l15 & 7)) * 8)]);
                if (act0)
                    o[0][jt] = __builtin_amdgcn_mfma_f32_16x16x32_bf16(pf0, vf, o[0][jt], 0, 0, 0);
                o[1][jt] = __builtin_amdgcn_mfma_f32_16x16x32_bf16(pf1, vf, o[1][jt], 0, 0, 0);
            }
        }

        __syncthreads();  // drain K(kb+1); all waves' Vt/Ps reads complete
    }

    // epilogue: one shuffle reduction per row, normalize, store bf16
#pragma unroll
    for (int s = 0; s < 2; s++) {
#pragma unroll
        for (int r = 0; r < 4; r++) {
            float l = lsum[s][r];
#pragma unroll
            for (int mk = 1; mk <= 8; mk <<= 1) l += __shfl_xor(l, mk);
            float inv = 1.f / l;
            int trow = q0 + s * 64 + w * 16 + quad * 4 + r;
            ushort* orow = attn + (size_t)trow * (HQ * D_HEAD) + h * D_HEAD;
#pragma unroll
            for (int jt = 0; jt < 8; jt++)
                orow[jt * 16 + l15] = f2bf(o[s][jt][r] * inv);
        }
    }
}

// ---------------- launch ----------------
extern "C" void kernel_launch(void* const* d_in, const int* in_sizes, int n_in,
                              void* d_out, int out_size, void* d_ws, size_t ws_size,
                              hipStream_t stream) {
    const float* hidden = (const float*)d_in[0];
    const float* cosb = (const float*)d_in[2];
    const float* sinb = (const float*)d_in[3];
    const float* Wq = (const float*)d_in[4];
    const float* Wk = (const float*)d_in[5];
    const float* Wv = (const float*)d_in[6];
    const float* Wo = (const float*)d_in[7];
    float* out = (float*)d_out;

    char* ws = (char*)d_ws;
    ushort* hiddenB = (ushort*)(ws);                          // 16 MB: T x HID bf16
    ushort* WqkvT   = (ushort*)(ws + (size_t)(16u << 20));    // 48 MB: [6144][4096] bf16
    ushort* WoT     = (ushort*)(ws + (size_t)(64u << 20));    // 32 MB: [4096][4096] bf16
    ushort* qkv     = (ushort*)(ws + (size_t)(96u << 20));    // 24 MB: T x 6144 bf16
    ushort* attnO   = (ushort*)(ws + (size_t)(120u << 20));   // 16 MB: T x 4096 bf16
    ushort* VtG     = (ushort*)(ws + (size_t)(136u << 20));   // 4 MB: [HKV][128][2048] bf16
    // total 140 MB

    cast_f32_bf16<<<8192, 256, 0, stream>>>(hidden, hiddenB, T_DIM * HID);
    transpose_cast<<<dim3(64, 64), 256, 0, stream>>>(Wq, WqkvT, HID, 4096);
    transpose_cast<<<dim3(16, 64), 256, 0, stream>>>(Wk, WqkvT + (size_t)4096 * HID, HID, 1024);
    transpose_cast<<<dim3(16, 64), 256, 0, stream>>>(Wv, WqkvT + (size_t)5120 * HID, HID, 1024);
    transpose_cast<<<dim3(64, 64), 256, 0, stream>>>(Wo, WoT, HID, 4096);

    // qkv = hidden @ [Wq|Wk|Wv]   (M=2048, N=6144, K=4096), bf16 out; 256 blocks = 1/CU
    gemm_qkv<<<dim3(8, 32), 512, 0, stream>>>(hiddenB, WqkvT, qkv, HID, HID, HID, QKV_N);
    rope_kernel<<<T_DIM, 320, 0, stream>>>(qkv, cosb, sinb);
    transpose_v<<<dim3(64, 4, 8), 256, 0, stream>>>(qkv, VtG);
    attn_kernel<<<dim3(T_DIM / 128, HQ), 256, 0, stream>>>(qkv, VtG, attnO);
    // out = attnO @ Wo  (M=2048, N=4096, K=4096), fp32 out; 256 blocks = 1/CU
    gemm_out<<<dim3(8, 32), 512, 0, stream>>>(attnO, WoT, out, HID, HID, HID, HID);
}

// Round 5
// 536.848 us; speedup vs baseline: 1.0406x; 1.0406x over previous
//
#include <hip/hip_runtime.h>
#include <hip/hip_bf16.h>
#include <cstdint>
#include <cstddef>

// Problem constants
#define T_DIM   2048
#define HID     4096
#define HQ      32
#define HKV     8
#define D_HEAD  128
#define QKV_N   6144   // 4096 Q + 1024 K + 1024 V
#define KOFF    4096
#define VOFF    5120

typedef __attribute__((ext_vector_type(8))) short short8;   // 8 bf16 (4 VGPRs)
typedef __attribute__((ext_vector_type(4))) float floatx4;  // MFMA C/D frag

__device__ __forceinline__ ushort f2bf(float f) {
    union { float f; uint u; } v; v.f = f;
    uint r = v.u + 0x7fffu + ((v.u >> 16) & 1u);  // RNE
    return (ushort)(r >> 16);
}
__device__ __forceinline__ float bf2f(ushort h) {
    union { uint u; float f; } v; v.u = ((uint)h) << 16; return v.f;
}
// 8 bf16 from 8B-aligned LDS
__device__ __forceinline__ short8 ld8(const ushort* p) {
    uint2 a = *(const uint2*)p, b = *(const uint2*)(p + 4);
    union { uint u[4]; short8 s; } x;
    x.u[0] = a.x; x.u[1] = a.y; x.u[2] = b.x; x.u[3] = b.y;
    return x.s;
}
// async global->LDS, 16B per lane. LDS dest must be wave-uniform base + lane*16.
__device__ __forceinline__ void gld_lds16(const ushort* g, ushort* l) {
    __builtin_amdgcn_global_load_lds(
        (__attribute__((address_space(1))) void*)(g),
        (__attribute__((address_space(3))) void*)(l), 16, 0, 0);
}

// ---------------- elementwise cast fp32 -> bf16 ----------------
__global__ void cast_f32_bf16(const float* __restrict__ in, ushort* __restrict__ out, int n) {
    int i = (blockIdx.x * blockDim.x + threadIdx.x) * 4;
    if (i < n) {
        float4 v = *(const float4*)(in + i);
        ushort4 o;
        o.x = f2bf(v.x); o.y = f2bf(v.y); o.z = f2bf(v.z); o.w = f2bf(v.w);
        *(ushort4*)(out + i) = o;
    }
}

// ---------------- transpose + cast: W[K][N] fp32 -> Wt[N][K] bf16 ----------------
__global__ __launch_bounds__(256) void transpose_cast(const float* __restrict__ W,
                                                      ushort* __restrict__ Wt, int K, int N) {
    __shared__ ushort tile[64][72];
    int n0 = blockIdx.x * 64, k0 = blockIdx.y * 64;
    int tx = threadIdx.x & 15, ty = threadIdx.x >> 4;  // 16 x 16
#pragma unroll
    for (int i = 0; i < 4; i++) {
        int r = ty + i * 16;  // k-row
        float4 v = *(const float4*)&W[(size_t)(k0 + r) * N + n0 + tx * 4];
        tile[tx * 4 + 0][r] = f2bf(v.x);
        tile[tx * 4 + 1][r] = f2bf(v.y);
        tile[tx * 4 + 2][r] = f2bf(v.z);
        tile[tx * 4 + 3][r] = f2bf(v.w);
    }
    __syncthreads();
#pragma unroll
    for (int i = 0; i < 2; i++) {
        int task = i * 256 + threadIdx.x;
        int nr = task >> 3, c = task & 7;
        short8 o = *(const short8*)&tile[nr][c * 8];
        *(short8*)&Wt[(size_t)(n0 + nr) * K + k0 + c * 8] = o;
    }
}

// ---------------- transpose V slice of qkv -> VtG[kvh][d][t] (t contiguous) ----------------
__global__ void transpose_v(const ushort* __restrict__ qkv, ushort* __restrict__ VtG) {
    __shared__ ushort tile[32][33];
    int t0 = blockIdx.x * 32, d0 = blockIdx.y * 32, kvh = blockIdx.z;
    int tx = threadIdx.x & 31, ty = threadIdx.x >> 5;  // 32 x 8
#pragma unroll
    for (int i = 0; i < 4; i++) {
        int t = t0 + ty + i * 8;
        tile[ty + i * 8][tx] = qkv[(size_t)t * QKV_N + VOFF + kvh * D_HEAD + d0 + tx];
    }
    __syncthreads();
#pragma unroll
    for (int i = 0; i < 4; i++) {
        int d = d0 + ty + i * 8;
        VtG[((size_t)kvh * D_HEAD + d) * T_DIM + t0 + tx] = tile[tx][ty + i * 8];
    }
}

// ---------------- bf16 MFMA GEMM: C[M][N] = A[M][K] * Bt[N][K]^T ----------------
// 128x128 tile, 4 waves (2x2 of 64x64), 16x16x32 MFMA, BK=32, double-buffered.
// ~3 blocks/CU: inter-block overlap hides the barrier vmcnt drain (m114).
// XCD-aware swizzle (T1): 1D grid, bid%8 = XCD. XCD k owns M-bands {2k,2k+1}
// for ALL N-bands -> per-XCD A-footprint = 2 MB (L2-resident, fetched ~once);
// only B streams through L2. Cuts L2-miss/L3/HBM feed traffic ~3x.
// Requires gridDim.x = 16 * NY (M-tiles fixed at 16 = 2048/128).
template <typename OutT>
__global__ __launch_bounds__(256) void gemm_bt(const ushort* __restrict__ A,
                                               const ushort* __restrict__ Bt,
                                               OutT* __restrict__ C,
                                               int K, int lda, int ldb, int ldc) {
    __shared__ ushort As[2][128 * 32];
    __shared__ ushort Bs[2][128 * 32];
    int tid = threadIdx.x;
    int w = tid >> 6, lane = tid & 63, quad = lane >> 4, l15 = lane & 15;
    int wr = (w >> 1) * 64, wc = (w & 1) * 64;
    int bid = blockIdx.x;
    int xb = ((bid & 7) << 1) | ((bid >> 3) & 1);   // M-band: XCD k -> {2k, 2k+1}
    int yb = bid >> 4;                              // N-band
    int m0 = xb * 128, n0 = yb * 128;

    floatx4 acc[4][4];
    floatx4 z = {0.f, 0.f, 0.f, 0.f};
#pragma unroll
    for (int i = 0; i < 4; i++)
#pragma unroll
        for (int j = 0; j < 4; j++) acc[i][j] = z;

    int arow = tid >> 2, ac = (tid & 3) * 8;
    const ushort* gA0 = A + (size_t)(m0 + arow) * lda + ac;
    const ushort* gA1 = A + (size_t)(m0 + arow + 64) * lda + ac;
    const ushort* gB0 = Bt + (size_t)(n0 + arow) * ldb + ac;
    const ushort* gB1 = Bt + (size_t)(n0 + arow + 64) * ldb + ac;

    gld_lds16(gA0, &As[0][tid * 8]);
    gld_lds16(gA1, &As[0][64 * 32 + tid * 8]);
    gld_lds16(gB0, &Bs[0][tid * 8]);
    gld_lds16(gB1, &Bs[0][64 * 32 + tid * 8]);
    gA0 += 32; gA1 += 32; gB0 += 32; gB1 += 32;

    int cur = 0;
    for (int k0 = 0; k0 < K; k0 += 32, cur ^= 1) {
        __syncthreads();
        if (k0 + 32 < K) {
            gld_lds16(gA0, &As[cur ^ 1][tid * 8]);
            gld_lds16(gA1, &As[cur ^ 1][64 * 32 + tid * 8]);
            gld_lds16(gB0, &Bs[cur ^ 1][tid * 8]);
            gld_lds16(gB1, &Bs[cur ^ 1][64 * 32 + tid * 8]);
            gA0 += 32; gA1 += 32; gB0 += 32; gB1 += 32;
        }

        short8 af[4];
#pragma unroll
        for (int i = 0; i < 4; i++)
            af[i] = *(const short8*)&As[cur][(wr + i * 16 + l15) * 32 + quad * 8];
#pragma unroll
        for (int j = 0; j < 4; j++) {
            short8 bf = *(const short8*)&Bs[cur][(wc + j * 16 + l15) * 32 + quad * 8];
#pragma unroll
            for (int i = 0; i < 4; i++)
                acc[i][j] = __builtin_amdgcn_mfma_f32_16x16x32_bf16(af[i], bf, acc[i][j], 0, 0, 0);
        }
    }

#pragma unroll
    for (int i = 0; i < 4; i++) {
        int row0 = m0 + wr + i * 16 + quad * 4;
#pragma unroll
        for (int j = 0; j < 4; j++) {
            int col = n0 + wc + j * 16 + l15;
#pragma unroll
            for (int r = 0; r < 4; r++) {
                float v = acc[i][j][r];
                if constexpr (sizeof(OutT) == 2)
                    C[(size_t)(row0 + r) * ldc + col] = (OutT)f2bf(v);
                else
                    C[(size_t)(row0 + r) * ldc + col] = v;
            }
        }
    }
}

// ---------------- RoPE in-place on Q and K slices of qkv ----------------
__global__ __launch_bounds__(320) void rope_kernel(ushort* __restrict__ qkv,
                                                   const float* __restrict__ cosb,
                                                   const float* __restrict__ sinb) {
    int t = blockIdx.x;
    ushort* row = qkv + (size_t)t * QKV_N;
    const float* cr = cosb + (size_t)t * D_HEAD;
    const float* sr = sinb + (size_t)t * D_HEAD;
    int task = threadIdx.x;            // 0..319
    int slice = task >> 3, d8 = (task & 7) * 8;
    int col = slice * 128 + d8;
    short8 a = *(const short8*)&row[col];
    short8 b = *(const short8*)&row[col + 64];
    float4 c0 = *(const float4*)&cr[d8], c1 = *(const float4*)&cr[d8 + 4];
    float4 s0 = *(const float4*)&sr[d8], s1 = *(const float4*)&sr[d8 + 4];
    short8 oa, ob;
#pragma unroll
    for (int j = 0; j < 8; j++) {
        float cs = (j < 4) ? ((j == 0) ? c0.x : (j == 1) ? c0.y : (j == 2) ? c0.z : c0.w)
                           : ((j == 4) ? c1.x : (j == 5) ? c1.y : (j == 6) ? c1.z : c1.w);
        float sn = (j < 4) ? ((j == 0) ? s0.x : (j == 1) ? s0.y : (j == 2) ? s0.z : s0.w)
                           : ((j == 4) ? s1.x : (j == 5) ? s1.y : (j == 6) ? s1.z : s1.w);
        float x0 = bf2f((ushort)a[j]), x1 = bf2f((ushort)b[j]);
        oa[j] = (short)f2bf(x0 * cs - x1 * sn);
        ob[j] = (short)f2bf(x1 * cs + x0 * sn);
    }
    *(short8*)&row[col] = oa;
    *(short8*)&row[col + 64] = ob;
}

// ---------------- flash-style causal GQA attention ----------------
// XCD-aware mapping: 1D grid of 512; bid%8 = XCD = kvh group. Each XCD's 64
// blocks (4 heads x 16 q-tiles) share the SAME 1 MB K/V working set -> stays
// L2-resident per XCD. Heavy q-tiles dispatch first (qt descending in slot).
#define PS_STRIDE 68

__global__ __launch_bounds__(256, 2) void attn_kernel(const ushort* __restrict__ qkv,
                                                      const ushort* __restrict__ VtG,
                                                      ushort* __restrict__ attn) {
    __shared__ ushort Ks[64 * 128];         // 16384 B, swizzled
    __shared__ ushort Vt[128 * 64];         // 16384 B, swizzled
    __shared__ ushort Ps[128 * PS_STRIDE];  // 17408 B  (total 50176 B -> 3 blocks/CU)

    int bid = blockIdx.x;
    int kvh = bid & 7;                      // GQA group == XCD
    int s = bid >> 3;                       // 0..63
    int qt = 15 - (s >> 2);                 // heavy tiles first within XCD
    int h = (kvh << 2) | (s & 3);
    int q0 = qt * 128;
    int kbmax = 2 * qt + 1;
    int tid = threadIdx.x, w = tid >> 6, lane = tid & 63, quad = lane >> 4, l15 = lane & 15;

    const ushort* kbase = qkv + (size_t)KOFF + (size_t)kvh * D_HEAD;
    const ushort* vbase = VtG + (size_t)kvh * D_HEAD * T_DIM;

    const ushort* ksrc[4];
    const ushort* vsrc[4];
#pragma unroll
    for (int i = 0; i < 4; i++) {
        int cid = i * 256 + tid;
        int kr = cid >> 4, kp = cid & 15, kc = kp ^ (kr & 15);
        ksrc[i] = kbase + (size_t)kr * QKV_N + kc * 8;
        int vr = cid >> 3, vp = cid & 7, vc = vp ^ (vr & 7);
        vsrc[i] = vbase + (size_t)vr * T_DIM + vc * 8;
    }

    // prologue: issue K(0) loads (latency covered by the Q-frag loads below)
#pragma unroll
    for (int i = 0; i < 4; i++) {
        gld_lds16(ksrc[i], &Ks[(i * 256 + tid) * 8]);
        ksrc[i] += (size_t)64 * QKV_N;
    }

    // Q A-frags for both strips, direct from global (one-time scattered read)
    short8 qf[2][4];
#pragma unroll
    for (int s2 = 0; s2 < 2; s2++) {
        const ushort* qrow = qkv + (size_t)(q0 + s2 * 64 + w * 16 + l15) * QKV_N + h * D_HEAD + quad * 8;
#pragma unroll
        for (int ks = 0; ks < 4; ks++)
            qf[s2][ks] = *(const short8*)(qrow + ks * 32);
    }

    floatx4 o[2][8];
    floatx4 z = {0.f, 0.f, 0.f, 0.f};
#pragma unroll
    for (int s2 = 0; s2 < 2; s2++)
#pragma unroll
        for (int j = 0; j < 8; j++) o[s2][j] = z;
    float lsum[2][4] = {{0.f, 0.f, 0.f, 0.f}, {0.f, 0.f, 0.f, 0.f}};

    const float scale_l2e = 0.08838834764831845f * 1.4426950408889634f;  // D^-0.5 * log2(e)
    const float BOUND = 24.0f;

    __syncthreads();  // drain K(0)

    for (int kb = 0; kb <= kbmax; kb++) {
        bool act0 = (kb <= 2 * qt);  // strip0 fully masked on the final iteration

        // issue V(kb) loads (drained at mid-barrier; covered by QK compute)
#pragma unroll
        for (int i = 0; i < 4; i++) {
            gld_lds16(vsrc[i], &Vt[(i * 256 + tid) * 8]);
            vsrc[i] += 64;
        }

        // S = Q K^T for both strips; swizzled K frag reads shared across strips
        floatx4 sc[2][4];
#pragma unroll
        for (int s2 = 0; s2 < 2; s2++)
#pragma unroll
            for (int jt = 0; jt < 4; jt++) sc[s2][jt] = z;
#pragma unroll
        for (int ks = 0; ks < 4; ks++) {
#pragma unroll
            for (int jt = 0; jt < 4; jt++) {
                short8 kf = ld8(&Ks[(jt * 16 + l15) * 128 + (((ks * 4 + quad) ^ l15) * 8)]);
                if (act0)
                    sc[0][jt] = __builtin_amdgcn_mfma_f32_16x16x32_bf16(qf[0][ks], kf, sc[0][jt], 0, 0, 0);
                sc[1][jt] = __builtin_amdgcn_mfma_f32_16x16x32_bf16(qf[1][ks], kf, sc[1][jt], 0, 0, 0);
            }
        }

        // fixed-bound softmax; Ps rows are wave-private (lgkmcnt handles RAW)
#pragma unroll
        for (int s2 = 0; s2 < 2; s2++) {
            if (s2 == 0 && !act0) continue;
            bool diag = (kb == 2 * qt + s2);
#pragma unroll
            for (int r = 0; r < 4; r++) {
                int rloc = w * 16 + quad * 4 + r;  // row within strip
#pragma unroll
                for (int jt = 0; jt < 4; jt++) {
                    float v = fmaf(sc[s2][jt][r], scale_l2e, -BOUND);
                    if (diag && (jt * 16 + l15 > rloc)) v = -1e30f;
                    float p = exp2f(v);
                    lsum[s2][r] += p;
                    Ps[(s2 * 64 + rloc) * PS_STRIDE + jt * 16 + l15] = f2bf(p);
                }
            }
        }

        __syncthreads();  // drain V(kb); all waves' Ks reads complete

        // issue K(kb+1) loads (drained at end-barrier; covered by PV compute)
        if (kb < kbmax) {
#pragma unroll
            for (int i = 0; i < 4; i++) {
                gld_lds16(ksrc[i], &Ks[(i * 256 + tid) * 8]);
                ksrc[i] += (size_t)64 * QKV_N;
            }
        }

        // O += P V ; swizzled V frag reads shared across strips
#pragma unroll
        for (int ks2 = 0; ks2 < 2; ks2++) {
            short8 pf0 = ld8(&Ps[(w * 16 + l15) * PS_STRIDE + ks2 * 32 + quad * 8]);
            short8 pf1 = ld8(&Ps[(64 + w * 16 + l15) * PS_STRIDE + ks2 * 32 + quad * 8]);
#pragma unroll
            for (int jt = 0; jt < 8; jt++) {
                short8 vf = ld8(&Vt[(jt * 16 + l15) * 64 + (((ks2 * 4 + quad) ^ (l15 & 7)) * 8)]);
                if (act0)
                    o[0][jt] = __builtin_amdgcn_mfma_f32_16x16x32_bf16(pf0, vf, o[0][jt], 0, 0, 0);
                o[1][jt] = __builtin_amdgcn_mfma_f32_16x16x32_bf16(pf1, vf, o[1][jt], 0, 0, 0);
            }
        }

        __syncthreads();  // drain K(kb+1); all waves' Vt/Ps reads complete
    }

    // epilogue: one shuffle reduction per row, normalize, store bf16
#pragma unroll
    for (int s2 = 0; s2 < 2; s2++) {
#pragma unroll
        for (int r = 0; r < 4; r++) {
            float l = lsum[s2][r];
#pragma unroll
            for (int mk = 1; mk <= 8; mk <<= 1) l += __shfl_xor(l, mk);
            float inv = 1.f / l;
            int trow = q0 + s2 * 64 + w * 16 + quad * 4 + r;
            ushort* orow = attn + (size_t)trow * (HQ * D_HEAD) + h * D_HEAD;
#pragma unroll
            for (int jt = 0; jt < 8; jt++)
                orow[jt * 16 + l15] = f2bf(o[s2][jt][r] * inv);
        }
    }
}

// ---------------- launch ----------------
extern "C" void kernel_launch(void* const* d_in, const int* in_sizes, int n_in,
                              void* d_out, int out_size, void* d_ws, size_t ws_size,
                              hipStream_t stream) {
    const float* hidden = (const float*)d_in[0];
    const float* cosb = (const float*)d_in[2];
    const float* sinb = (const float*)d_in[3];
    const float* Wq = (const float*)d_in[4];
    const float* Wk = (const float*)d_in[5];
    const float* Wv = (const float*)d_in[6];
    const float* Wo = (const float*)d_in[7];
    float* out = (float*)d_out;

    char* ws = (char*)d_ws;
    ushort* hiddenB = (ushort*)(ws);                          // 16 MB: T x HID bf16
    ushort* WqkvT   = (ushort*)(ws + (size_t)(16u << 20));    // 48 MB: [6144][4096] bf16
    ushort* WoT     = (ushort*)(ws + (size_t)(64u << 20));    // 32 MB: [4096][4096] bf16
    ushort* qkv     = (ushort*)(ws + (size_t)(96u << 20));    // 24 MB: T x 6144 bf16
    ushort* attnO   = (ushort*)(ws + (size_t)(120u << 20));   // 16 MB: T x 4096 bf16
    ushort* VtG     = (ushort*)(ws + (size_t)(136u << 20));   // 4 MB: [HKV][128][2048] bf16
    // total 140 MB

    cast_f32_bf16<<<8192, 256, 0, stream>>>(hidden, hiddenB, T_DIM * HID);
    transpose_cast<<<dim3(64, 64), 256, 0, stream>>>(Wq, WqkvT, HID, 4096);
    transpose_cast<<<dim3(16, 64), 256, 0, stream>>>(Wk, WqkvT + (size_t)4096 * HID, HID, 1024);
    transpose_cast<<<dim3(16, 64), 256, 0, stream>>>(Wv, WqkvT + (size_t)5120 * HID, HID, 1024);
    transpose_cast<<<dim3(64, 64), 256, 0, stream>>>(Wo, WoT, HID, 4096);

    // qkv = hidden @ [Wq|Wk|Wv]   (M=2048, N=6144, K=4096), bf16 out
    // 1D grid 768 = 16 M-bands x 48 N-bands, XCD-swizzled (bid%8 -> M-band pair)
    gemm_bt<ushort><<<768, 256, 0, stream>>>(hiddenB, WqkvT, qkv,
                                             HID, HID, HID, QKV_N);
    rope_kernel<<<T_DIM, 320, 0, stream>>>(qkv, cosb, sinb);
    transpose_v<<<dim3(64, 4, 8), 256, 0, stream>>>(qkv, VtG);
    // 1D grid 512 = 8 kvh-groups (XCD) x 4 heads x 16 q-tiles
    attn_kernel<<<512, 256, 0, stream>>>(qkv, VtG, attnO);
    // out = attnO @ Wo  (M=2048, N=4096, K=4096), fp32 out; 512 = 16 x 32 XCD-swizzled
    gemm_bt<float><<<512, 256, 0, stream>>>(attnO, WoT, out,
                                            HID, HID, HID, HID);
}

// Round 7
// 515.642 us; speedup vs baseline: 1.0834x; 1.0411x over previous
//
#include <hip/hip_runtime.h>
#include <hip/hip_bf16.h>
#include <cstdint>
#include <cstddef>

// Problem constants
#define T_DIM   2048
#define HID     4096
#define HQ      32
#define HKV     8
#define D_HEAD  128
#define QKV_N   6144   // 4096 Q + 1024 K + 1024 V
#define KOFF    4096
#define VOFF    5120

typedef __attribute__((ext_vector_type(8))) short short8;   // 8 bf16 (4 VGPRs)
typedef __attribute__((ext_vector_type(4))) float floatx4;  // MFMA C/D frag

__device__ __forceinline__ ushort f2bf(float f) {
    union { float f; uint u; } v; v.f = f;
    uint r = v.u + 0x7fffu + ((v.u >> 16) & 1u);  // RNE
    return (ushort)(r >> 16);
}
__device__ __forceinline__ float bf2f(ushort h) {
    union { uint u; float f; } v; v.u = ((uint)h) << 16; return v.f;
}
// 8 bf16 from 8B-aligned LDS
__device__ __forceinline__ short8 ld8(const ushort* p) {
    uint2 a = *(const uint2*)p, b = *(const uint2*)(p + 4);
    union { uint u[4]; short8 s; } x;
    x.u[0] = a.x; x.u[1] = a.y; x.u[2] = b.x; x.u[3] = b.y;
    return x.s;
}
// async global->LDS, 16B per lane. LDS dest must be wave-uniform base + lane*16.
__device__ __forceinline__ void gld_lds16(const ushort* g, ushort* l) {
    __builtin_amdgcn_global_load_lds(
        (__attribute__((address_space(1))) void*)(g),
        (__attribute__((address_space(3))) void*)(l), 16, 0, 0);
}

// ================= fused preprocessing: cast + 4 weight transposes =================
// One dispatch replaces 5. Block ranges:
//   [0, 8192)        : hidden fp32 -> bf16 cast (1024 elems/block)
//   [8192, 12288)    : Wq  [4096][4096] -> WqkvT rows 0..4095
//   [12288, 13312)   : Wk  [4096][1024] -> WqkvT rows 4096..5119
//   [13312, 14336)   : Wv  [4096][1024] -> WqkvT rows 5120..6143
//   [14336, 18432)   : Wo  [4096][4096] -> WoT
__global__ __launch_bounds__(256) void preproc(const float* __restrict__ hidden,
                                               ushort* __restrict__ hiddenB,
                                               const float* __restrict__ Wq,
                                               const float* __restrict__ Wk,
                                               const float* __restrict__ Wv,
                                               const float* __restrict__ Wo,
                                               ushort* __restrict__ WqkvT,
                                               ushort* __restrict__ WoT) {
    __shared__ ushort tile[64][72];
    int bid = blockIdx.x, tid = threadIdx.x;

    if (bid < 8192) {  // cast path (block-uniform branch)
        int i = (bid * 256 + tid) * 4;
        float4 v = *(const float4*)(hidden + i);
        ushort4 o;
        o.x = f2bf(v.x); o.y = f2bf(v.y); o.z = f2bf(v.z); o.w = f2bf(v.w);
        *(ushort4*)(hiddenB + i) = o;
        return;
    }

    const float* W; ushort* Wt; int N, n0, k0;
    if (bid < 12288) {
        int r = bid - 8192;  W = Wq; Wt = WqkvT;                         N = 4096;
        n0 = (r & 63) * 64;  k0 = (r >> 6) * 64;
    } else if (bid < 13312) {
        int r = bid - 12288; W = Wk; Wt = WqkvT + (size_t)4096 * HID;    N = 1024;
        n0 = (r & 15) * 64;  k0 = (r >> 4) * 64;
    } else if (bid < 14336) {
        int r = bid - 13312; W = Wv; Wt = WqkvT + (size_t)5120 * HID;    N = 1024;
        n0 = (r & 15) * 64;  k0 = (r >> 4) * 64;
    } else {
        int r = bid - 14336; W = Wo; Wt = WoT;                           N = 4096;
        n0 = (r & 63) * 64;  k0 = (r >> 6) * 64;
    }

    int tx = tid & 15, ty = tid >> 4;  // 16 x 16
#pragma unroll
    for (int i = 0; i < 4; i++) {
        int r = ty + i * 16;  // k-row
        float4 v = *(const float4*)&W[(size_t)(k0 + r) * N + n0 + tx * 4];
        tile[tx * 4 + 0][r] = f2bf(v.x);
        tile[tx * 4 + 1][r] = f2bf(v.y);
        tile[tx * 4 + 2][r] = f2bf(v.z);
        tile[tx * 4 + 3][r] = f2bf(v.w);
    }
    __syncthreads();
#pragma unroll
    for (int i = 0; i < 2; i++) {
        int task = i * 256 + tid;
        int nr = task >> 3, c = task & 7;
        short8 o = *(const short8*)&tile[nr][c * 8];
        *(short8*)&Wt[(size_t)(n0 + nr) * HID + k0 + c * 8] = o;
    }
}

// ======== QKV GEMM with FUSED RoPE + V-transpose epilogue ========
// 128x128 tile, 4 waves, BK=32 double-buffered, XCD swizzle (bid%8 -> M-band pair).
// Each N-band (yb) is exactly one head slice of 128 cols, so the rope pair
// (d, d+64) is in-block. Epilogue: stage acc tile to LDS as bf16 (row-major,
// pad 132 -> conflict-free, 264B row stride keeps 8B alignment), then:
//   yb<32  : Q head yb      -> fp32 rope -> qkv cols yb*128 + d
//   32..39 : K head yb-32   -> fp32 rope -> qkv cols 4096 + kvh*128 + d
//   40..47 : V head yb-40   -> transpose -> VtG[kvh][d][m0+t]   (no qkv write)
// LDS: union overlays the proven 2D staging arrays (indexed like gemm_bt, no
// per-thread pointer arrays) with the epilogue [128][132] tile.
__global__ __launch_bounds__(256) void gemm_qkv_fused(const ushort* __restrict__ A,
                                                      const ushort* __restrict__ Bt,
                                                      ushort* __restrict__ qkv,
                                                      ushort* __restrict__ VtG,
                                                      const float* __restrict__ cosb,
                                                      const float* __restrict__ sinb) {
    struct Stage { ushort As[2][4096]; ushort Bs[2][4096]; };
    __shared__ union SmU { Stage st; ushort ep[16896]; } sm;  // 33792 B

    int tid = threadIdx.x;
    int w = tid >> 6, lane = tid & 63, quad = lane >> 4, l15 = lane & 15;
    int wr = (w >> 1) * 64, wc = (w & 1) * 64;
    int bid = blockIdx.x;
    int xb = ((bid & 7) << 1) | ((bid >> 3) & 1);   // M-band: XCD k -> {2k, 2k+1}
    int yb = bid >> 4;                              // N-band 0..47
    int m0 = xb * 128, n0 = yb * 128;

    floatx4 acc[4][4];
    floatx4 z = {0.f, 0.f, 0.f, 0.f};
#pragma unroll
    for (int i = 0; i < 4; i++)
#pragma unroll
        for (int j = 0; j < 4; j++) acc[i][j] = z;

    int arow = tid >> 2, ac = (tid & 3) * 8;
    const ushort* gA0 = A + (size_t)(m0 + arow) * HID + ac;
    const ushort* gA1 = A + (size_t)(m0 + arow + 64) * HID + ac;
    const ushort* gB0 = Bt + (size_t)(n0 + arow) * HID + ac;
    const ushort* gB1 = Bt + (size_t)(n0 + arow + 64) * HID + ac;

    gld_lds16(gA0, &sm.st.As[0][tid * 8]);
    gld_lds16(gA1, &sm.st.As[0][64 * 32 + tid * 8]);
    gld_lds16(gB0, &sm.st.Bs[0][tid * 8]);
    gld_lds16(gB1, &sm.st.Bs[0][64 * 32 + tid * 8]);
    gA0 += 32; gA1 += 32; gB0 += 32; gB1 += 32;

    int cur = 0;
    for (int k0 = 0; k0 < HID; k0 += 32, cur ^= 1) {
        __syncthreads();
        if (k0 + 32 < HID) {
            gld_lds16(gA0, &sm.st.As[cur ^ 1][tid * 8]);
            gld_lds16(gA1, &sm.st.As[cur ^ 1][64 * 32 + tid * 8]);
            gld_lds16(gB0, &sm.st.Bs[cur ^ 1][tid * 8]);
            gld_lds16(gB1, &sm.st.Bs[cur ^ 1][64 * 32 + tid * 8]);
            gA0 += 32; gA1 += 32; gB0 += 32; gB1 += 32;
        }

        short8 af[4];
#pragma unroll
        for (int i = 0; i < 4; i++)
            af[i] = *(const short8*)&sm.st.As[cur][(wr + i * 16 + l15) * 32 + quad * 8];
#pragma unroll
        for (int j = 0; j < 4; j++) {
            short8 bf = *(const short8*)&sm.st.Bs[cur][(wc + j * 16 + l15) * 32 + quad * 8];
#pragma unroll
            for (int i = 0; i < 4; i++)
                acc[i][j] = __builtin_amdgcn_mfma_f32_16x16x32_bf16(af[i], bf, acc[i][j], 0, 0, 0);
        }
    }

    // ---- epilogue: stage tile to LDS (bf16, row-major pad 132) ----
    __syncthreads();  // all staging reads done; safe to reuse LDS via union
#pragma unroll
    for (int i = 0; i < 4; i++) {
        int row0 = wr + i * 16 + quad * 4;
#pragma unroll
        for (int j = 0; j < 4; j++) {
            int col = wc + j * 16 + l15;
#pragma unroll
            for (int r = 0; r < 4; r++)
                sm.ep[(row0 + r) * 132 + col] = f2bf(acc[i][j][r]);
        }
    }
    __syncthreads();

    if (yb < 40) {
        // Q or K head: rope in fp32, write qkv
        int colbase = (yb < 32) ? yb * 128 : (KOFF + (yb - 32) * 128);
#pragma unroll
        for (int it = 0; it < 4; ++it) {
            int task = it * 256 + tid;       // 1024 tasks = 128 t x 8 chunks
            int t = task >> 3, d8 = (task & 7) * 8;
            int tg = m0 + t;
            short8 a = ld8(&sm.ep[t * 132 + d8]);
            short8 b = ld8(&sm.ep[t * 132 + 64 + d8]);
            const float* cr = cosb + (size_t)tg * D_HEAD + d8;
            const float* sr = sinb + (size_t)tg * D_HEAD + d8;
            float4 c0 = *(const float4*)cr, c1 = *(const float4*)(cr + 4);
            float4 s0 = *(const float4*)sr, s1 = *(const float4*)(sr + 4);
            short8 oa, ob;
#pragma unroll
            for (int j = 0; j < 8; j++) {
                float cs = (j < 4) ? ((j == 0) ? c0.x : (j == 1) ? c0.y : (j == 2) ? c0.z : c0.w)
                                   : ((j == 4) ? c1.x : (j == 5) ? c1.y : (j == 6) ? c1.z : c1.w);
                float sn = (j < 4) ? ((j == 0) ? s0.x : (j == 1) ? s0.y : (j == 2) ? s0.z : s0.w)
                                   : ((j == 4) ? s1.x : (j == 5) ? s1.y : (j == 6) ? s1.z : s1.w);
                float x0 = bf2f((ushort)a[j]), x1 = bf2f((ushort)b[j]);
                oa[j] = (short)f2bf(x0 * cs - x1 * sn);
                ob[j] = (short)f2bf(x1 * cs + x0 * sn);
            }
            *(short8*)&qkv[(size_t)tg * QKV_N + colbase + d8] = oa;
            *(short8*)&qkv[(size_t)tg * QKV_N + colbase + 64 + d8] = ob;
        }
    } else {
        // V head: transpose tile -> VtG[kvh][d][t], coalesced along t
        int kvh = yb - 40;
#pragma unroll
        for (int it = 0; it < 8; ++it) {
            int task = it * 256 + tid;       // 2048 tasks = 128 d x 16 t-chunks
            int d = task >> 4, tc = (task & 15) * 8;
            short8 o;
#pragma unroll
            for (int j = 0; j < 8; j++) o[j] = (short)sm.ep[(tc + j) * 132 + d];
            *(short8*)&VtG[((size_t)kvh * D_HEAD + d) * T_DIM + m0 + tc] = o;
        }
    }
}

// ---------------- bf16 MFMA GEMM (O-proj): C[M][N] = A[M][K] * Bt[N][K]^T ----------------
template <typename OutT>
__global__ __launch_bounds__(256) void gemm_bt(const ushort* __restrict__ A,
                                               const ushort* __restrict__ Bt,
                                               OutT* __restrict__ C,
                                               int K, int lda, int ldb, int ldc) {
    __shared__ ushort As[2][128 * 32];
    __shared__ ushort Bs[2][128 * 32];
    int tid = threadIdx.x;
    int w = tid >> 6, lane = tid & 63, quad = lane >> 4, l15 = lane & 15;
    int wr = (w >> 1) * 64, wc = (w & 1) * 64;
    int bid = blockIdx.x;
    int xb = ((bid & 7) << 1) | ((bid >> 3) & 1);   // M-band: XCD k -> {2k, 2k+1}
    int yb = bid >> 4;                              // N-band
    int m0 = xb * 128, n0 = yb * 128;

    floatx4 acc[4][4];
    floatx4 z = {0.f, 0.f, 0.f, 0.f};
#pragma unroll
    for (int i = 0; i < 4; i++)
#pragma unroll
        for (int j = 0; j < 4; j++) acc[i][j] = z;

    int arow = tid >> 2, ac = (tid & 3) * 8;
    const ushort* gA0 = A + (size_t)(m0 + arow) * lda + ac;
    const ushort* gA1 = A + (size_t)(m0 + arow + 64) * lda + ac;
    const ushort* gB0 = Bt + (size_t)(n0 + arow) * ldb + ac;
    const ushort* gB1 = Bt + (size_t)(n0 + arow + 64) * ldb + ac;

    gld_lds16(gA0, &As[0][tid * 8]);
    gld_lds16(gA1, &As[0][64 * 32 + tid * 8]);
    gld_lds16(gB0, &Bs[0][tid * 8]);
    gld_lds16(gB1, &Bs[0][64 * 32 + tid * 8]);
    gA0 += 32; gA1 += 32; gB0 += 32; gB1 += 32;

    int cur = 0;
    for (int k0 = 0; k0 < K; k0 += 32, cur ^= 1) {
        __syncthreads();
        if (k0 + 32 < K) {
            gld_lds16(gA0, &As[cur ^ 1][tid * 8]);
            gld_lds16(gA1, &As[cur ^ 1][64 * 32 + tid * 8]);
            gld_lds16(gB0, &Bs[cur ^ 1][tid * 8]);
            gld_lds16(gB1, &Bs[cur ^ 1][64 * 32 + tid * 8]);
            gA0 += 32; gA1 += 32; gB0 += 32; gB1 += 32;
        }

        short8 af[4];
#pragma unroll
        for (int i = 0; i < 4; i++)
            af[i] = *(const short8*)&As[cur][(wr + i * 16 + l15) * 32 + quad * 8];
#pragma unroll
        for (int j = 0; j < 4; j++) {
            short8 bf = *(const short8*)&Bs[cur][(wc + j * 16 + l15) * 32 + quad * 8];
#pragma unroll
            for (int i = 0; i < 4; i++)
                acc[i][j] = __builtin_amdgcn_mfma_f32_16x16x32_bf16(af[i], bf, acc[i][j], 0, 0, 0);
        }
    }

#pragma unroll
    for (int i = 0; i < 4; i++) {
        int row0 = m0 + wr + i * 16 + quad * 4;
#pragma unroll
        for (int j = 0; j < 4; j++) {
            int col = n0 + wc + j * 16 + l15;
#pragma unroll
            for (int r = 0; r < 4; r++) {
                float v = acc[i][j][r];
                if constexpr (sizeof(OutT) == 2)
                    C[(size_t)(row0 + r) * ldc + col] = (OutT)f2bf(v);
                else
                    C[(size_t)(row0 + r) * ldc + col] = v;
            }
        }
    }
}

// ---------------- flash-style causal GQA attention ----------------
// XCD-aware mapping: 1D grid of 512; bid%8 = XCD = kvh group. Each XCD's 64
// blocks (4 heads x 16 q-tiles) share the SAME 1 MB K/V working set -> stays
// L2-resident per XCD. Heavy q-tiles dispatch first (qt descending in slot).
#define PS_STRIDE 68

__global__ __launch_bounds__(256, 2) void attn_kernel(const ushort* __restrict__ qkv,
                                                      const ushort* __restrict__ VtG,
                                                      ushort* __restrict__ attn) {
    __shared__ ushort Ks[64 * 128];         // 16384 B, swizzled
    __shared__ ushort Vt[128 * 64];         // 16384 B, swizzled
    __shared__ ushort Ps[128 * PS_STRIDE];  // 17408 B  (total 50176 B -> 3 blocks/CU)

    int bid = blockIdx.x;
    int kvh = bid & 7;                      // GQA group == XCD
    int s = bid >> 3;                       // 0..63
    int qt = 15 - (s >> 2);                 // heavy tiles first within XCD
    int h = (kvh << 2) | (s & 3);
    int q0 = qt * 128;
    int kbmax = 2 * qt + 1;
    int tid = threadIdx.x, w = tid >> 6, lane = tid & 63, quad = lane >> 4, l15 = lane & 15;

    const ushort* kbase = qkv + (size_t)KOFF + (size_t)kvh * D_HEAD;
    const ushort* vbase = VtG + (size_t)kvh * D_HEAD * T_DIM;

    const ushort* ksrc[4];
    const ushort* vsrc[4];
#pragma unroll
    for (int i = 0; i < 4; i++) {
        int cid = i * 256 + tid;
        int kr = cid >> 4, kp = cid & 15, kc = kp ^ (kr & 15);
        ksrc[i] = kbase + (size_t)kr * QKV_N + kc * 8;
        int vr = cid >> 3, vp = cid & 7, vc = vp ^ (vr & 7);
        vsrc[i] = vbase + (size_t)vr * T_DIM + vc * 8;
    }

    // prologue: issue K(0) loads (latency covered by the Q-frag loads below)
#pragma unroll
    for (int i = 0; i < 4; i++) {
        gld_lds16(ksrc[i], &Ks[(i * 256 + tid) * 8]);
        ksrc[i] += (size_t)64 * QKV_N;
    }

    // Q A-frags for both strips, direct from global (one-time scattered read)
    short8 qf[2][4];
#pragma unroll
    for (int s2 = 0; s2 < 2; s2++) {
        const ushort* qrow = qkv + (size_t)(q0 + s2 * 64 + w * 16 + l15) * QKV_N + h * D_HEAD + quad * 8;
#pragma unroll
        for (int ks = 0; ks < 4; ks++)
            qf[s2][ks] = *(const short8*)(qrow + ks * 32);
    }

    floatx4 o[2][8];
    floatx4 z = {0.f, 0.f, 0.f, 0.f};
#pragma unroll
    for (int s2 = 0; s2 < 2; s2++)
#pragma unroll
        for (int j = 0; j < 8; j++) o[s2][j] = z;
    float lsum[2][4] = {{0.f, 0.f, 0.f, 0.f}, {0.f, 0.f, 0.f, 0.f}};

    const float scale_l2e = 0.08838834764831845f * 1.4426950408889634f;  // D^-0.5 * log2(e)
    const float BOUND = 24.0f;

    __syncthreads();  // drain K(0)

    for (int kb = 0; kb <= kbmax; kb++) {
        bool act0 = (kb <= 2 * qt);  // strip0 fully masked on the final iteration

        // issue V(kb) loads (drained at mid-barrier; covered by QK compute)
#pragma unroll
        for (int i = 0; i < 4; i++) {
            gld_lds16(vsrc[i], &Vt[(i * 256 + tid) * 8]);
            vsrc[i] += 64;
        }

        // S = Q K^T for both strips; swizzled K frag reads shared across strips
        floatx4 sc[2][4];
#pragma unroll
        for (int s2 = 0; s2 < 2; s2++)
#pragma unroll
            for (int jt = 0; jt < 4; jt++) sc[s2][jt] = z;
#pragma unroll
        for (int ks = 0; ks < 4; ks++) {
#pragma unroll
            for (int jt = 0; jt < 4; jt++) {
                short8 kf = ld8(&Ks[(jt * 16 + l15) * 128 + (((ks * 4 + quad) ^ l15) * 8)]);
                if (act0)
                    sc[0][jt] = __builtin_amdgcn_mfma_f32_16x16x32_bf16(qf[0][ks], kf, sc[0][jt], 0, 0, 0);
                sc[1][jt] = __builtin_amdgcn_mfma_f32_16x16x32_bf16(qf[1][ks], kf, sc[1][jt], 0, 0, 0);
            }
        }

        // fixed-bound softmax; Ps rows are wave-private (lgkmcnt handles RAW)
#pragma unroll
        for (int s2 = 0; s2 < 2; s2++) {
            if (s2 == 0 && !act0) continue;
            bool diag = (kb == 2 * qt + s2);
#pragma unroll
            for (int r = 0; r < 4; r++) {
                int rloc = w * 16 + quad * 4 + r;  // row within strip
#pragma unroll
                for (int jt = 0; jt < 4; jt++) {
                    float v = fmaf(sc[s2][jt][r], scale_l2e, -BOUND);
                    if (diag && (jt * 16 + l15 > rloc)) v = -1e30f;
                    float p = exp2f(v);
                    lsum[s2][r] += p;
                    Ps[(s2 * 64 + rloc) * PS_STRIDE + jt * 16 + l15] = f2bf(p);
                }
            }
        }

        __syncthreads();  // drain V(kb); all waves' Ks reads complete

        // issue K(kb+1) loads (drained at end-barrier; covered by PV compute)
        if (kb < kbmax) {
#pragma unroll
            for (int i = 0; i < 4; i++) {
                gld_lds16(ksrc[i], &Ks[(i * 256 + tid) * 8]);
                ksrc[i] += (size_t)64 * QKV_N;
            }
        }

        // O += P V ; swizzled V frag reads shared across strips
#pragma unroll
        for (int ks2 = 0; ks2 < 2; ks2++) {
            short8 pf0 = ld8(&Ps[(w * 16 + l15) * PS_STRIDE + ks2 * 32 + quad * 8]);
            short8 pf1 = ld8(&Ps[(64 + w * 16 + l15) * PS_STRIDE + ks2 * 32 + quad * 8]);
#pragma unroll
            for (int jt = 0; jt < 8; jt++) {
                short8 vf = ld8(&Vt[(jt * 16 + l15) * 64 + (((ks2 * 4 + quad) ^ (l15 & 7)) * 8)]);
                if (act0)
                    o[0][jt] = __builtin_amdgcn_mfma_f32_16x16x32_bf16(pf0, vf, o[0][jt], 0, 0, 0);
                o[1][jt] = __builtin_amdgcn_mfma_f32_16x16x32_bf16(pf1, vf, o[1][jt], 0, 0, 0);
            }
        }

        __syncthreads();  // drain K(kb+1); all waves' Vt/Ps reads complete
    }

    // epilogue: one shuffle reduction per row, normalize, store bf16
#pragma unroll
    for (int s2 = 0; s2 < 2; s2++) {
#pragma unroll
        for (int r = 0; r < 4; r++) {
            float l = lsum[s2][r];
#pragma unroll
            for (int mk = 1; mk <= 8; mk <<= 1) l += __shfl_xor(l, mk);
            float inv = 1.f / l;
            int trow = q0 + s2 * 64 + w * 16 + quad * 4 + r;
            ushort* orow = attn + (size_t)trow * (HQ * D_HEAD) + h * D_HEAD;
#pragma unroll
            for (int jt = 0; jt < 8; jt++)
                orow[jt * 16 + l15] = f2bf(o[s2][jt][r] * inv);
        }
    }
}

// ---------------- launch ----------------
extern "C" void kernel_launch(void* const* d_in, const int* in_sizes, int n_in,
                              void* d_out, int out_size, void* d_ws, size_t ws_size,
                              hipStream_t stream) {
    const float* hidden = (const float*)d_in[0];
    const float* cosb = (const float*)d_in[2];
    const float* sinb = (const float*)d_in[3];
    const float* Wq = (const float*)d_in[4];
    const float* Wk = (const float*)d_in[5];
    const float* Wv = (const float*)d_in[6];
    const float* Wo = (const float*)d_in[7];
    float* out = (float*)d_out;

    char* ws = (char*)d_ws;
    ushort* hiddenB = (ushort*)(ws);                          // 16 MB: T x HID bf16
    ushort* WqkvT   = (ushort*)(ws + (size_t)(16u << 20));    // 48 MB: [6144][4096] bf16
    ushort* WoT     = (ushort*)(ws + (size_t)(64u << 20));    // 32 MB: [4096][4096] bf16
    ushort* qkv     = (ushort*)(ws + (size_t)(96u << 20));    // 24 MB: T x 6144 bf16
    ushort* attnO   = (ushort*)(ws + (size_t)(120u << 20));   // 16 MB: T x 4096 bf16
    ushort* VtG     = (ushort*)(ws + (size_t)(136u << 20));   // 4 MB: [HKV][128][2048] bf16
    // total 140 MB

    // 1: cast + all 4 weight transposes
    preproc<<<18432, 256, 0, stream>>>(hidden, hiddenB, Wq, Wk, Wv, Wo, WqkvT, WoT);
    // 2: qkv = hidden @ [Wq|Wk|Wv] with fused rope (Q,K) + V-transpose to VtG
    gemm_qkv_fused<<<768, 256, 0, stream>>>(hiddenB, WqkvT, qkv, VtG, cosb, sinb);
    // 3: attention
    attn_kernel<<<512, 256, 0, stream>>>(qkv, VtG, attnO);
    // 4: out = attnO @ Wo  (fp32 out), XCD-swizzled 512 = 16 x 32
    gemm_bt<float><<<512, 256, 0, stream>>>(attnO, WoT, out, HID, HID, HID, HID);
}